// Round 30
// baseline (83.422 us; speedup 1.0000x reference)
//
#include <hip/hip_runtime.h>
#include <hip/hip_bf16.h>

#define NREL 5000
#define NBIN 32
#define NEDGE 200000
#define DIM 512
#define NHEAD 8
#define CAP 256

typedef __attribute__((ext_vector_type(8))) short short8;
typedef __attribute__((ext_vector_type(4))) short short4v;
typedef __attribute__((ext_vector_type(4))) float f32x4;
typedef unsigned short ushort_t;

#define REL_N (NREL * DIM)
#define BIN_N (NBIN * DIM)
#define WATTN_N (DIM * 3 * DIM)
#define WAGGR_N (DIM * DIM)
#define CTOT (REL_N + BIN_N + WATTN_N + WAGGR_N)
#define CONV_BLOCKS (CTOT / 4 / 256)

__device__ __forceinline__ float b2f(ushort_t u) {
  unsigned int v = ((unsigned int)u) << 16;
  union { unsigned int i; float f; } c; c.i = v; return c.f;
}
__device__ __forceinline__ ushort_t f2b_rne(float f) {
  union { float f; unsigned int u; } c; c.f = f;
  unsigned int u = c.u;
  return (ushort_t)((u + 0x7FFFu + ((u >> 16) & 1u)) >> 16);
}
__device__ __forceinline__ void gload16(const void* g, void* l) {
  __builtin_amdgcn_global_load_lds(
      (const __attribute__((address_space(1))) void*)g,
      (__attribute__((address_space(3))) void*)l, 16, 0, 0);
}
template<int CTRL>
__device__ __forceinline__ float dpp_add(float x) {
  int v = __builtin_amdgcn_update_dpp(0, __float_as_int(x), CTRL, 0xF, 0xF, true);
  return x + __int_as_float(v);
}

// ---------- launch 1: convert 4 MFMA tensors f32->bf16; blocks 0..19 zero cur ----------
__global__ void conv_k(const float* __restrict__ s_rel, const float* __restrict__ s_bin,
                       const float* __restrict__ s_wattn, const float* __restrict__ s_waggr,
                       ushort_t* __restrict__ dst, int* __restrict__ cur) {
  int b = blockIdx.x;
  if (b < 20) {
    int i = b * 256 + threadIdx.x;
    if (i < NREL) cur[i] = 0;
  }
  const int O1 = REL_N, O2 = O1 + BIN_N, O3 = O2 + WATTN_N;
  int i4 = (b * 256 + threadIdx.x) * 4;
  const float* src; int j;
  if (i4 < O1)      { src = s_rel;   j = i4; }
  else if (i4 < O2) { src = s_bin;   j = i4 - O1; }
  else if (i4 < O3) { src = s_wattn; j = i4 - O2; }
  else              { src = s_waggr; j = i4 - O3; }
  float4 v = *(const float4*)(src + j);
  short4v o;
  o[0] = (short)f2b_rne(v.x); o[1] = (short)f2b_rne(v.y);
  o[2] = (short)f2b_rne(v.z); o[3] = (short)f2b_rne(v.w);
  *(short4v*)(dst + i4) = o;
}

// ---------- launch 2: gload_lds GEMM (64x128, BK=64, XOR swizzle) + bucket-scatter
__global__ __launch_bounds__(256) void gemm_scatter_k(
    const ushort_t* __restrict__ c_rel, const ushort_t* __restrict__ c_bin,
    const ushort_t* __restrict__ c_wattn, const float* __restrict__ b_attn,
    const ushort_t* __restrict__ c_waggr, const float* __restrict__ b_aggr,
    ushort_t* __restrict__ P1B, ushort_t* __restrict__ PM, ushort_t* __restrict__ P2,
    const int* __restrict__ trip, int* __restrict__ cur, unsigned int* __restrict__ etb)
{
  __shared__ ushort_t Alds[64 * 64];    // 8 KB
  __shared__ ushort_t Blds[128 * 64];   // 16 KB
  int bx = blockIdx.x, by = blockIdx.y;
  if (by >= 12) {
    int sid = (by - 12) * 80 + bx;      // 0..319
    for (int i = threadIdx.x; i < 625; i += 256) {
      int e = sid * 625 + i;            // 320*625 = 200000 exact
      int h  = trip[3 * e];
      int ta = trip[3 * e + 1];
      int bi = trip[3 * e + 2];
      h  = min(max(h, 0), NREL - 1);
      ta = min(max(ta, 0), NREL - 1);
      bi = min(max(bi, 0), NBIN - 1);
      int p = atomicAdd(&cur[h], 1);
      if (p < CAP)
        etb[(h << 8) + p] = ((unsigned int)ta << 11) | ((unsigned int)bi << 24);
    }
    return;
  }
  const ushort_t* A; int Arows;
  const ushort_t* Bbase; int Bld; int joff;
  const float* bias;
  ushort_t* OUT; int OUTld; int ocolOff;
  int rbase;
  if (bx == 79) {
    if (by >= 4) return;
    A = c_bin; Arows = NBIN; rbase = 0;
    Bbase = c_wattn + 512; Bld = 3 * DIM; joff = 0;
    bias = b_attn;
    OUT = P2; OUTld = DIM; ocolOff = 0;
  } else {
    A = c_rel; Arows = NREL; rbase = bx * 64;
    int seg = by >> 2;
    if (seg == 2)      { Bbase = c_waggr;        Bld = DIM;     bias = b_aggr; }
    else if (seg == 1) { Bbase = c_wattn + 1024; Bld = 3 * DIM; bias = nullptr; }
    else               { Bbase = c_wattn;        Bld = 3 * DIM; bias = nullptr; }
    joff = seg * 512;
    OUT = (seg == 0) ? P1B : PM;
    OUTld = (seg == 0) ? DIM : 1024;
    ocolOff = (seg == 0) ? 0 : 512;
  }
  int tid = threadIdx.x;
  int l = tid & 63, wv = tid >> 6;
  int ctb = by * 128;
  int lr = l >> 3;
  int srcslot = (l & 7) ^ lr;           // pre-swizzled global k-slot (XOR involution)
  const ushort_t* aS0; const ushort_t* aS1;
  const ushort_t* bS0; const ushort_t* bS1; const ushort_t* bS2; const ushort_t* bS3;
  {
    int a0 = wv * 16 + 0 * 8 + lr, a1 = wv * 16 + 1 * 8 + lr;
    aS0 = A + (size_t)min(rbase + a0, Arows - 1) * DIM + srcslot * 8;
    aS1 = A + (size_t)min(rbase + a1, Arows - 1) * DIM + srcslot * 8;
    int c0 = wv * 32 + 0 * 8 + lr, c1 = wv * 32 + 1 * 8 + lr,
        c2 = wv * 32 + 2 * 8 + lr, c3 = wv * 32 + 3 * 8 + lr;
    bS0 = Bbase + (size_t)(ctb + c0 - joff) * Bld + srcslot * 8;
    bS1 = Bbase + (size_t)(ctb + c1 - joff) * Bld + srcslot * 8;
    bS2 = Bbase + (size_t)(ctb + c2 - joff) * Bld + srcslot * 8;
    bS3 = Bbase + (size_t)(ctb + c3 - joff) * Bld + srcslot * 8;
  }
  ushort_t* aD0 = Alds + (wv * 16 + 0) * 64;
  ushort_t* aD1 = Alds + (wv * 16 + 8) * 64;
  ushort_t* bD0 = Blds + (wv * 32 + 0) * 64;
  ushort_t* bD1 = Blds + (wv * 32 + 8) * 64;
  ushort_t* bD2 = Blds + (wv * 32 + 16) * 64;
  ushort_t* bD3 = Blds + (wv * 32 + 24) * 64;

  f32x4 acc[4][2] = {};
  for (int kk = 0; kk < DIM; kk += 64) {
    gload16(aS0 + kk, aD0); gload16(aS1 + kk, aD1);
    gload16(bS0 + kk, bD0); gload16(bS1 + kk, bD1);
    gload16(bS2 + kk, bD2); gload16(bS3 + kk, bD3);
    __syncthreads();                    // drains vmcnt before barrier
#pragma unroll
    for (int ks = 0; ks < 2; ++ks) {
      int sg = ks * 4 + (l >> 4);
      int sw = (sg ^ (l & 7)) * 8;      // swizzled LDS slot offset (elems)
      short8 aF[4], bF[2];
#pragma unroll
      for (int m2 = 0; m2 < 4; ++m2) {
        int mrow = m2 * 16 + (l & 15);
        aF[m2] = *(const short8*)(Alds + mrow * 64 + sw);
      }
#pragma unroll
      for (int n = 0; n < 2; ++n) {
        int crow = wv * 32 + n * 16 + (l & 15);
        bF[n] = *(const short8*)(Blds + crow * 64 + sw);
      }
#pragma unroll
      for (int m2 = 0; m2 < 4; ++m2)
#pragma unroll
        for (int n = 0; n < 2; ++n)
          acc[m2][n] = __builtin_amdgcn_mfma_f32_16x16x32_bf16(aF[m2], bF[n], acc[m2][n], 0, 0, 0);
    }
    __syncthreads();                    // all ds_reads done before restage
  }
  int r0 = rbase + (l >> 4) * 4;
#pragma unroll
  for (int n = 0; n < 2; ++n) {
    int col = ctb + wv * 32 + n * 16 + (l & 15);
    float bv = bias ? bias[col - joff] : 0.0f;
    int ocol = col - ocolOff;
#pragma unroll
    for (int m2 = 0; m2 < 4; ++m2) {
#pragma unroll
      for (int jj = 0; jj < 4; ++jj) {
        int row = r0 + m2 * 16 + jj;
        if (row < Arows) OUT[(size_t)row * OUTld + ocol] = f2b_rne(acc[m2][n][jj] + bv);
      }
    }
  }
}

// ---------- launch 3: aggregation — 32-lane edge groups (4 lanes/head, 16 dims/lane)
// 2 waves/relation x 2 groups/wave = 4 partials/relation; serial depth ~10 edges
__global__ __launch_bounds__(256, 4) void aggr2_k(
    const int* __restrict__ cur, const unsigned int* __restrict__ etb,
    const ushort_t* __restrict__ P1B, const ushort_t* __restrict__ PM,
    const ushort_t* __restrict__ P2, const float* __restrict__ avec,
    float* __restrict__ outf)
{
  // shmem phase 1: [0,32768) = P2 copy (bf16 32x512)
  // shmem phase 2: [0,16384) = red[8][512] f32; [16384,16896) = ms[8][8][2] f32
  __shared__ __align__(16) char shmem[32 * DIM * 2];

  int t = threadIdx.x;
  int l = t & 63, wv = t >> 6;
  int p = wv >> 1, sub = wv & 1;      // relation within block; wave within relation
  int g = l >> 5;                     // 32-lane edge group
  int ll = l & 31;
  int r = blockIdx.x * 2 + p;
  int nE = min(cur[r], CAP);
  int base = r << 8;
  int half = nE >> 1;
  int start = sub ? half : 0;
  int cnt = sub ? (nE - half) : half;

  int hd1 = ll >> 2;                  // head (4 lanes per head)
  int ob = ll * 16;                   // first of this lane's 16 dims
  int b32 = ll * 32;                  // byte offset of this lane's 32B

  // ---- preload all of P2 (32 KB) into LDS: 8 x short8 per thread ----
  {
    ushort_t* p2dst = (ushort_t*)shmem;
#pragma unroll
    for (int i = 0; i < 8; ++i) {
      int idx = t * 8 + i * 2048;
      *(short8*)(p2dst + idx) = *(const short8*)(P2 + idx);
    }
  }

  float p1v[16], avv[16];
  {
    short8 pa = *(const short8*)(P1B + (size_t)r * DIM + ob);
    short8 pb = *(const short8*)(P1B + (size_t)r * DIM + ob + 8);
#pragma unroll
    for (int j = 0; j < 8; ++j) {
      p1v[j] = b2f((ushort_t)pa[j]);
      p1v[j + 8] = b2f((ushort_t)pb[j]);
    }
#pragma unroll
    for (int j = 0; j < 16; ++j) avv[j] = avec[ob + j];
  }
  float acc[16] = {};
  float m = -INFINITY, s = 0.0f;

  const char* PMc = (const char*)PM;
  const char* p2lds = (const char*)shmem;

  __syncthreads();                  // P2 staged before any edge reads it

  for (int ck = 0; ck < cnt; ck += 64) {
    int ne = min(64, cnt - ck);
    unsigned int tbreg = 0;
    if (l < ne) tbreg = etb[base + start + ck + l];
    for (int k = 0; 2 * k < ne; ++k) {
      int idx = 2 * k + g;
      unsigned int tb = (unsigned int)__shfl((int)tbreg, idx);
      if (idx < ne) {
        const char* row_ = PMc + (tb & 0x00FFFFFFu);
        const char* p2r = p2lds + ((tb >> 24) << 10) + b32;
        short8 p2a = *(const short8*)(p2r);
        short8 p2b = *(const short8*)(p2r + 16);
        short8 p3a = *(const short8*)(row_ + b32);
        short8 p3b = *(const short8*)(row_ + b32 + 16);
        short8 mva = *(const short8*)(row_ + 1024 + b32);
        short8 mvb = *(const short8*)(row_ + 1024 + b32 + 16);
        float pt0 = 0.f, pt1 = 0.f, pt2 = 0.f, pt3 = 0.f;
#pragma unroll
        for (int j = 0; j < 4; ++j) {
          float z0 = p1v[j]      + b2f((ushort_t)p2a[j])     + b2f((ushort_t)p3a[j]);
          float z1 = p1v[j + 4]  + b2f((ushort_t)p2a[j + 4]) + b2f((ushort_t)p3a[j + 4]);
          float z2 = p1v[j + 8]  + b2f((ushort_t)p2b[j])     + b2f((ushort_t)p3b[j]);
          float z3 = p1v[j + 12] + b2f((ushort_t)p2b[j + 4]) + b2f((ushort_t)p3b[j + 4]);
          pt0 += z0 * (z0 > 0.f ? avv[j]      : 0.2f * avv[j]);
          pt1 += z1 * (z1 > 0.f ? avv[j + 4]  : 0.2f * avv[j + 4]);
          pt2 += z2 * (z2 > 0.f ? avv[j + 8]  : 0.2f * avv[j + 8]);
          pt3 += z3 * (z3 > 0.f ? avv[j + 12] : 0.2f * avv[j + 12]);
        }
        float part = (pt0 + pt1) + (pt2 + pt3);
        part = dpp_add<0xB1>(part);   // xor 1 (quad_perm [1,0,3,2])
        part = dpp_add<0x4E>(part);   // xor 2 (quad_perm [2,3,0,1]) -> head reduce done
        if (part > m + 8.0f) {        // defer-max rescale (quad-uniform branch)
          float f = __expf(m - part);
          s *= f;
#pragma unroll
          for (int j = 0; j < 16; ++j) acc[j] *= f;
          m = part;
        }
        float ev = __expf(part - m);
        s += ev;
#pragma unroll
        for (int j = 0; j < 8; ++j) acc[j] += ev * b2f((ushort_t)mva[j]);
#pragma unroll
        for (int j = 0; j < 8; ++j) acc[j + 8] += ev * b2f((ushort_t)mvb[j]);
      }
    }
  }

  // ---- merge the 4 partials per relation (reuse shmem: red[8][512] + ms) ----
  __syncthreads();                  // all waves done reading P2 from shmem
  float* red = (float*)shmem;                       // [8][512]
  float* ms  = (float*)(shmem + 16384);             // [8][8][2]
  int q = p * 4 + sub * 2 + g;      // partial index within block (0..7)
#pragma unroll
  for (int j = 0; j < 16; ++j) red[q * DIM + ob + j] = acc[j];
  if ((ll & 3) == 0) { ms[(q * NHEAD + hd1) * 2] = m; ms[(q * NHEAD + hd1) * 2 + 1] = s; }
  __syncthreads();

  int pp = t >> 7;
  int d0 = (t & 127) * 4;
  int h = d0 >> 6;
  int rr = blockIdx.x * 2 + pp;
  int q0 = pp * 4;
  float m0 = ms[((q0)     * NHEAD + h) * 2], s0 = ms[((q0)     * NHEAD + h) * 2 + 1];
  float m1 = ms[((q0 + 1) * NHEAD + h) * 2], s1 = ms[((q0 + 1) * NHEAD + h) * 2 + 1];
  float m2 = ms[((q0 + 2) * NHEAD + h) * 2], s2 = ms[((q0 + 2) * NHEAD + h) * 2 + 1];
  float m3 = ms[((q0 + 3) * NHEAD + h) * 2], s3 = ms[((q0 + 3) * NHEAD + h) * 2 + 1];
  float M = fmaxf(fmaxf(m0, m1), fmaxf(m2, m3));
  float c0 = (m0 == M) ? 1.0f : __expf(m0 - M);
  float c1 = (m1 == M) ? 1.0f : __expf(m1 - M);
  float c2 = (m2 == M) ? 1.0f : __expf(m2 - M);
  float c3 = (m3 == M) ? 1.0f : __expf(m3 - M);
  float S = s0 * c0 + s1 * c1 + s2 * c2 + s3 * c3;
  float inv = 1.0f / (S + 1e-16f);
  float4 val;
#pragma unroll
  for (int dj = 0; dj < 4; ++dj) {
    float v = red[q0 * DIM + d0 + dj] * c0 + red[(q0 + 1) * DIM + d0 + dj] * c1 +
              red[(q0 + 2) * DIM + d0 + dj] * c2 + red[(q0 + 3) * DIM + d0 + dj] * c3;
    ((float*)&val)[dj] = v * inv;
  }
  *(float4*)(outf + (size_t)rr * DIM + d0) = val;
}

extern "C" void kernel_launch(void* const* d_in, const int* in_sizes, int n_in,
                              void* d_out, int out_size, void* d_ws, size_t ws_size,
                              hipStream_t stream) {
  const float* s_rel   = (const float*)d_in[0];
  const float* s_bin   = (const float*)d_in[1];
  const int*   trip    = (const int*)d_in[2];     // int32
  const float* s_wattn = (const float*)d_in[3];
  const float* b_attn  = (const float*)d_in[4];
  const float* avec    = (const float*)d_in[5];
  const float* s_waggr = (const float*)d_in[6];
  const float* b_aggr  = (const float*)d_in[7];

  ushort_t* canon = (ushort_t*)d_ws;
  ushort_t* c_rel   = canon;
  ushort_t* c_bin   = c_rel + REL_N;
  ushort_t* c_wattn = c_bin + BIN_N;
  ushort_t* c_waggr = c_wattn + WATTN_N;
  int* cur = (int*)(c_waggr + WAGGR_N);             // NREL
  unsigned int* etb = (unsigned int*)(cur + NREL);  // NREL*CAP
  ushort_t* P1B = (ushort_t*)(((uintptr_t)(etb + NREL * CAP) + 15) & ~(uintptr_t)15);
  ushort_t* PM  = P1B + (size_t)NREL * DIM;
  ushort_t* P2  = PM + (size_t)NREL * 1024;

  conv_k<<<CONV_BLOCKS, 256, 0, stream>>>(s_rel, s_bin, s_wattn, s_waggr, canon, cur);

  dim3 gg(80, 16);
  gemm_scatter_k<<<gg, 256, 0, stream>>>(c_rel, c_bin, c_wattn, b_attn, c_waggr, b_aggr,
                                         P1B, PM, P2, trip, cur, etb);

  aggr2_k<<<NREL / 2, 256, 0, stream>>>(cur, etb, P1B, PM, P2, avec, (float*)d_out);
}

// Round 31
// 80.878 us; speedup vs baseline: 1.0315x; 1.0315x over previous
//
#include <hip/hip_runtime.h>
#include <hip/hip_bf16.h>

#define NREL 5000
#define NBIN 32
#define NEDGE 200000
#define DIM 512
#define NHEAD 8
#define CAP 256

typedef __attribute__((ext_vector_type(8))) short short8;
typedef __attribute__((ext_vector_type(4))) short short4v;
typedef __attribute__((ext_vector_type(4))) float f32x4;
typedef unsigned short ushort_t;

#define REL_N (NREL * DIM)
#define BIN_N (NBIN * DIM)
#define WATTN_N (DIM * 3 * DIM)
#define WAGGR_N (DIM * DIM)
#define CTOT (REL_N + BIN_N + WATTN_N + WAGGR_N)
#define CONV_BLOCKS (CTOT / 4 / 256)

__device__ __forceinline__ float b2f(ushort_t u) {
  unsigned int v = ((unsigned int)u) << 16;
  union { unsigned int i; float f; } c; c.i = v; return c.f;
}
__device__ __forceinline__ ushort_t f2b_rne(float f) {
  union { float f; unsigned int u; } c; c.f = f;
  unsigned int u = c.u;
  return (ushort_t)((u + 0x7FFFu + ((u >> 16) & 1u)) >> 16);
}
__device__ __forceinline__ void gload16(const void* g, void* l) {
  __builtin_amdgcn_global_load_lds(
      (const __attribute__((address_space(1))) void*)g,
      (__attribute__((address_space(3))) void*)l, 16, 0, 0);
}
// DPP quad-perm add (single-cycle VALU cross-lane within quads); CTRL literal
template<int CTRL>
__device__ __forceinline__ float dpp_add(float x) {
  int v = __builtin_amdgcn_update_dpp(0, __float_as_int(x), CTRL, 0xF, 0xF, true);
  return x + __int_as_float(v);
}

// ---------- launch 1: convert 4 MFMA tensors f32->bf16; blocks 0..19 zero cur ----------
__global__ void conv_k(const float* __restrict__ s_rel, const float* __restrict__ s_bin,
                       const float* __restrict__ s_wattn, const float* __restrict__ s_waggr,
                       ushort_t* __restrict__ dst, int* __restrict__ cur) {
  int b = blockIdx.x;
  if (b < 20) {
    int i = b * 256 + threadIdx.x;
    if (i < NREL) cur[i] = 0;
  }
  const int O1 = REL_N, O2 = O1 + BIN_N, O3 = O2 + WATTN_N;
  int i4 = (b * 256 + threadIdx.x) * 4;
  const float* src; int j;
  if (i4 < O1)      { src = s_rel;   j = i4; }
  else if (i4 < O2) { src = s_bin;   j = i4 - O1; }
  else if (i4 < O3) { src = s_wattn; j = i4 - O2; }
  else              { src = s_waggr; j = i4 - O3; }
  float4 v = *(const float4*)(src + j);
  short4v o;
  o[0] = (short)f2b_rne(v.x); o[1] = (short)f2b_rne(v.y);
  o[2] = (short)f2b_rne(v.z); o[3] = (short)f2b_rne(v.w);
  *(short4v*)(dst + i4) = o;
}

// ---------- launch 2: gload_lds GEMM (64x128, BK=64, XOR swizzle) + bucket-scatter
__global__ __launch_bounds__(256) void gemm_scatter_k(
    const ushort_t* __restrict__ c_rel, const ushort_t* __restrict__ c_bin,
    const ushort_t* __restrict__ c_wattn, const float* __restrict__ b_attn,
    const ushort_t* __restrict__ c_waggr, const float* __restrict__ b_aggr,
    ushort_t* __restrict__ P1B, ushort_t* __restrict__ PM, ushort_t* __restrict__ P2,
    const int* __restrict__ trip, int* __restrict__ cur, unsigned int* __restrict__ etb)
{
  __shared__ ushort_t Alds[64 * 64];    // 8 KB
  __shared__ ushort_t Blds[128 * 64];   // 16 KB
  int bx = blockIdx.x, by = blockIdx.y;
  if (by >= 12) {
    int sid = (by - 12) * 80 + bx;      // 0..319
    for (int i = threadIdx.x; i < 625; i += 256) {
      int e = sid * 625 + i;            // 320*625 = 200000 exact
      int h  = trip[3 * e];
      int ta = trip[3 * e + 1];
      int bi = trip[3 * e + 2];
      h  = min(max(h, 0), NREL - 1);
      ta = min(max(ta, 0), NREL - 1);
      bi = min(max(bi, 0), NBIN - 1);
      int p = atomicAdd(&cur[h], 1);
      if (p < CAP)
        etb[(h << 8) + p] = ((unsigned int)ta << 11) | ((unsigned int)bi << 24);
    }
    return;
  }
  const ushort_t* A; int Arows;
  const ushort_t* Bbase; int Bld; int joff;
  const float* bias;
  ushort_t* OUT; int OUTld; int ocolOff;
  int rbase;
  if (bx == 79) {
    if (by >= 4) return;
    A = c_bin; Arows = NBIN; rbase = 0;
    Bbase = c_wattn + 512; Bld = 3 * DIM; joff = 0;
    bias = b_attn;
    OUT = P2; OUTld = DIM; ocolOff = 0;
  } else {
    A = c_rel; Arows = NREL; rbase = bx * 64;
    int seg = by >> 2;
    if (seg == 2)      { Bbase = c_waggr;        Bld = DIM;     bias = b_aggr; }
    else if (seg == 1) { Bbase = c_wattn + 1024; Bld = 3 * DIM; bias = nullptr; }
    else               { Bbase = c_wattn;        Bld = 3 * DIM; bias = nullptr; }
    joff = seg * 512;
    OUT = (seg == 0) ? P1B : PM;
    OUTld = (seg == 0) ? DIM : 1024;
    ocolOff = (seg == 0) ? 0 : 512;
  }
  int tid = threadIdx.x;
  int l = tid & 63, wv = tid >> 6;
  int ctb = by * 128;
  int lr = l >> 3;
  int srcslot = (l & 7) ^ lr;           // pre-swizzled global k-slot (XOR involution)
  const ushort_t* aS0; const ushort_t* aS1;
  const ushort_t* bS0; const ushort_t* bS1; const ushort_t* bS2; const ushort_t* bS3;
  {
    int a0 = wv * 16 + 0 * 8 + lr, a1 = wv * 16 + 1 * 8 + lr;
    aS0 = A + (size_t)min(rbase + a0, Arows - 1) * DIM + srcslot * 8;
    aS1 = A + (size_t)min(rbase + a1, Arows - 1) * DIM + srcslot * 8;
    int c0 = wv * 32 + 0 * 8 + lr, c1 = wv * 32 + 1 * 8 + lr,
        c2 = wv * 32 + 2 * 8 + lr, c3 = wv * 32 + 3 * 8 + lr;
    bS0 = Bbase + (size_t)(ctb + c0 - joff) * Bld + srcslot * 8;
    bS1 = Bbase + (size_t)(ctb + c1 - joff) * Bld + srcslot * 8;
    bS2 = Bbase + (size_t)(ctb + c2 - joff) * Bld + srcslot * 8;
    bS3 = Bbase + (size_t)(ctb + c3 - joff) * Bld + srcslot * 8;
  }
  ushort_t* aD0 = Alds + (wv * 16 + 0) * 64;
  ushort_t* aD1 = Alds + (wv * 16 + 8) * 64;
  ushort_t* bD0 = Blds + (wv * 32 + 0) * 64;
  ushort_t* bD1 = Blds + (wv * 32 + 8) * 64;
  ushort_t* bD2 = Blds + (wv * 32 + 16) * 64;
  ushort_t* bD3 = Blds + (wv * 32 + 24) * 64;

  f32x4 acc[4][2] = {};
  for (int kk = 0; kk < DIM; kk += 64) {
    gload16(aS0 + kk, aD0); gload16(aS1 + kk, aD1);
    gload16(bS0 + kk, bD0); gload16(bS1 + kk, bD1);
    gload16(bS2 + kk, bD2); gload16(bS3 + kk, bD3);
    __syncthreads();                    // drains vmcnt before barrier
#pragma unroll
    for (int ks = 0; ks < 2; ++ks) {
      int sg = ks * 4 + (l >> 4);
      int sw = (sg ^ (l & 7)) * 8;      // swizzled LDS slot offset (elems)
      short8 aF[4], bF[2];
#pragma unroll
      for (int m2 = 0; m2 < 4; ++m2) {
        int mrow = m2 * 16 + (l & 15);
        aF[m2] = *(const short8*)(Alds + mrow * 64 + sw);
      }
#pragma unroll
      for (int n = 0; n < 2; ++n) {
        int crow = wv * 32 + n * 16 + (l & 15);
        bF[n] = *(const short8*)(Blds + crow * 64 + sw);
      }
#pragma unroll
      for (int m2 = 0; m2 < 4; ++m2)
#pragma unroll
        for (int n = 0; n < 2; ++n)
          acc[m2][n] = __builtin_amdgcn_mfma_f32_16x16x32_bf16(aF[m2], bF[n], acc[m2][n], 0, 0, 0);
    }
    __syncthreads();                    // all ds_reads done before restage
  }
  int r0 = rbase + (l >> 4) * 4;
#pragma unroll
  for (int n = 0; n < 2; ++n) {
    int col = ctb + wv * 32 + n * 16 + (l & 15);
    float bv = bias ? bias[col - joff] : 0.0f;
    int ocol = col - ocolOff;
#pragma unroll
    for (int m2 = 0; m2 < 4; ++m2) {
#pragma unroll
      for (int jj = 0; jj < 4; ++jj) {
        int row = r0 + m2 * 16 + jj;
        if (row < Arows) OUT[(size_t)row * OUTld + ocol] = f2b_rne(acc[m2][n][jj] + bv);
      }
    }
  }
}

// ---------- launch 3: aggregation (r29-proven: fused, P2 in LDS, DPP reduce) ----------
#define EDGE_LOAD(TB, P2V, P3V, MV)                                     \
  {                                                                     \
    const char* row_ = PMc + ((TB) & 0x00FFFFFFu);                      \
    P2V = *(const short8*)(p2lds + (((TB) >> 24) << 10) + l16);         \
    P3V = *(const short8*)(row_ + l16);                                 \
    MV  = *(const short8*)(row_ + 1024 + l16);                          \
  }

#define EDGE_COMPUTE(P2V, P3V, MV)                                      \
  {                                                                     \
    float part = 0.0f;                                                  \
    _Pragma("unroll")                                                   \
    for (int j = 0; j < 8; ++j) {                                       \
      float z = p1v[j] + b2f((ushort_t)P2V[j]) + b2f((ushort_t)P3V[j]); \
      part += z * (z > 0.f ? avv[j] : avv02[j]);                        \
    }                                                                   \
    part = dpp_add<0xB1>(part);   /* xor 1 (quad_perm [1,0,3,2]) */     \
    part = dpp_add<0x4E>(part);   /* xor 2 (quad_perm [2,3,0,1]) */     \
    part += __shfl_xor(part, 4);                                        \
    if (part > m + 8.0f) {                                              \
      float f = __expf(m - part);                                       \
      s *= f;                                                           \
      _Pragma("unroll")                                                 \
      for (int j = 0; j < 8; ++j) acc[j] *= f;                          \
      m = part;                                                         \
    }                                                                   \
    float ev = __expf(part - m);                                        \
    s += ev;                                                            \
    _Pragma("unroll")                                                   \
    for (int j = 0; j < 8; ++j) acc[j] += ev * b2f((ushort_t)MV[j]);    \
  }

__global__ __launch_bounds__(256, 6) void aggr2_k(
    const int* __restrict__ cur, const unsigned int* __restrict__ etb,
    const ushort_t* __restrict__ P1B, const ushort_t* __restrict__ PM,
    const ushort_t* __restrict__ P2, const float* __restrict__ avec,
    float* __restrict__ outf)
{
  // shmem phase 1: [0,32768) = P2 copy (bf16 32x512)
  // shmem phase 2: [0,8192) = red[4][512] f32; [8192,8448) = ms[4][8][2] f32
  __shared__ __align__(16) char shmem[32 * DIM * 2];

  int t = threadIdx.x;
  int l = t & 63, wv = t >> 6;
  int p = wv >> 1, sub = wv & 1;
  int r = blockIdx.x * 2 + p;
  int nE = min(cur[r], CAP);
  int base = r << 8;                // bucket base in etb
  int half = nE >> 1;
  int start = sub ? half : 0;
  int cnt = sub ? (nE - half) : half;

  int hd1 = l >> 3;
  int ob = l * 8;
  int l16 = l * 16;

  // ---- preload all of P2 (32 KB) into LDS: 8 x short8 per thread ----
  {
    ushort_t* p2dst = (ushort_t*)shmem;
#pragma unroll
    for (int i = 0; i < 8; ++i) {
      int idx = t * 8 + i * 2048;
      *(short8*)(p2dst + idx) = *(const short8*)(P2 + idx);
    }
  }

  float p1v[8], avv[8], avv02[8];
  {
    short8 p1b = *(const short8*)(P1B + (size_t)r * DIM + ob);
#pragma unroll
    for (int j = 0; j < 8; ++j) {
      p1v[j] = b2f((ushort_t)p1b[j]);
      float a = avec[ob + j];
      avv[j] = a;
      avv02[j] = 0.2f * a;
    }
  }
  float acc[8] = {};
  float m = -INFINITY, s = 0.0f;

  const char* PMc = (const char*)PM;
  const char* p2lds = (const char*)shmem;

  __syncthreads();                  // P2 staged before any edge reads it

  for (int ck = 0; ck < cnt; ck += 64) {
    int ne = min(64, cnt - ck);
    unsigned int tbreg = 0;
    if (l < ne) tbreg = etb[base + start + ck + l];
    short8 p2A, p3A, mvA, p2B, p3B, mvB;
    unsigned int tb0 = (unsigned int)__shfl((int)tbreg, 0);
    EDGE_LOAD(tb0, p2A, p3A, mvA);
    int i = 0;
    while (i + 1 < ne) {
      unsigned int tbb = (unsigned int)__shfl((int)tbreg, i + 1);
      EDGE_LOAD(tbb, p2B, p3B, mvB);
      EDGE_COMPUTE(p2A, p3A, mvA);
      if (i + 2 < ne) {
        unsigned int tba = (unsigned int)__shfl((int)tbreg, i + 2);
        EDGE_LOAD(tba, p2A, p3A, mvA);
      }
      EDGE_COMPUTE(p2B, p3B, mvB);
      i += 2;
    }
    if (i < ne) EDGE_COMPUTE(p2A, p3A, mvA);
  }

  // ---- merge the two half-relation waves (reuse shmem: red + ms overlay) ----
  __syncthreads();                  // all waves done reading P2 from shmem
  float* red = (float*)shmem;                       // [4][512]
  float* ms  = (float*)(shmem + 8192);              // [4][8][2]
#pragma unroll
  for (int j = 0; j < 8; ++j) red[wv * DIM + ob + j] = acc[j];
  if ((l & 7) == 0) { ms[(wv * NHEAD + hd1) * 2] = m; ms[(wv * NHEAD + hd1) * 2 + 1] = s; }
  __syncthreads();

  int pp = t >> 7;
  int d0 = (t & 127) * 4;
  int h = d0 >> 6;
  int rr = blockIdx.x * 2 + pp;
  float m1 = ms[((2 * pp) * NHEAD + h) * 2],     s1 = ms[((2 * pp) * NHEAD + h) * 2 + 1];
  float m2 = ms[((2 * pp + 1) * NHEAD + h) * 2], s2 = ms[((2 * pp + 1) * NHEAD + h) * 2 + 1];
  float M = fmaxf(m1, m2);
  float c1 = (m1 == M) ? 1.0f : __expf(m1 - M);
  float c2 = (m2 == M) ? 1.0f : __expf(m2 - M);
  float S = s1 * c1 + s2 * c2;
  float inv = 1.0f / (S + 1e-16f);
  float4 val;
  val.x = (red[(2 * pp) * DIM + d0]     * c1 + red[(2 * pp + 1) * DIM + d0]     * c2) * inv;
  val.y = (red[(2 * pp) * DIM + d0 + 1] * c1 + red[(2 * pp + 1) * DIM + d0 + 1] * c2) * inv;
  val.z = (red[(2 * pp) * DIM + d0 + 2] * c1 + red[(2 * pp + 1) * DIM + d0 + 2] * c2) * inv;
  val.w = (red[(2 * pp) * DIM + d0 + 3] * c1 + red[(2 * pp + 1) * DIM + d0 + 3] * c2) * inv;
  *(float4*)(outf + (size_t)rr * DIM + d0) = val;
}

extern "C" void kernel_launch(void* const* d_in, const int* in_sizes, int n_in,
                              void* d_out, int out_size, void* d_ws, size_t ws_size,
                              hipStream_t stream) {
  const float* s_rel   = (const float*)d_in[0];
  const float* s_bin   = (const float*)d_in[1];
  const int*   trip    = (const int*)d_in[2];     // int32
  const float* s_wattn = (const float*)d_in[3];
  const float* b_attn  = (const float*)d_in[4];
  const float* avec    = (const float*)d_in[5];
  const float* s_waggr = (const float*)d_in[6];
  const float* b_aggr  = (const float*)d_in[7];

  ushort_t* canon = (ushort_t*)d_ws;
  ushort_t* c_rel   = canon;
  ushort_t* c_bin   = c_rel + REL_N;
  ushort_t* c_wattn = c_bin + BIN_N;
  ushort_t* c_waggr = c_wattn + WATTN_N;
  int* cur = (int*)(c_waggr + WAGGR_N);             // NREL
  unsigned int* etb = (unsigned int*)(cur + NREL);  // NREL*CAP
  ushort_t* P1B = (ushort_t*)(((uintptr_t)(etb + NREL * CAP) + 15) & ~(uintptr_t)15);
  ushort_t* PM  = P1B + (size_t)NREL * DIM;
  ushort_t* P2  = PM + (size_t)NREL * 1024;

  conv_k<<<CONV_BLOCKS, 256, 0, stream>>>(s_rel, s_bin, s_wattn, s_waggr, canon, cur);

  dim3 gg(80, 16);
  gemm_scatter_k<<<gg, 256, 0, stream>>>(c_rel, c_bin, c_wattn, b_attn, c_waggr, b_aggr,
                                         P1B, PM, P2, trip, cur, etb);

  aggr2_k<<<NREL / 2, 256, 0, stream>>>(cur, etb, P1B, PM, P2, avec, (float*)d_out);
}

// Round 32
// 80.382 us; speedup vs baseline: 1.0378x; 1.0062x over previous
//
#include <hip/hip_runtime.h>
#include <hip/hip_bf16.h>

#define NREL 5000
#define NBIN 32
#define NEDGE 200000
#define DIM 512
#define NHEAD 8
#define CAP 256

typedef __attribute__((ext_vector_type(8))) short short8;
typedef __attribute__((ext_vector_type(4))) short short4v;
typedef __attribute__((ext_vector_type(4))) float f32x4;
typedef unsigned short ushort_t;

#define REL_N (NREL * DIM)
#define BIN_N (NBIN * DIM)
#define WATTN_N (DIM * 3 * DIM)
#define WAGGR_N (DIM * DIM)
#define CTOT (REL_N + BIN_N + WATTN_N + WAGGR_N)
#define CONV_BLOCKS (CTOT / 4 / 256)

__device__ __forceinline__ float b2f(ushort_t u) {
  unsigned int v = ((unsigned int)u) << 16;
  union { unsigned int i; float f; } c; c.i = v; return c.f;
}
__device__ __forceinline__ ushort_t f2b_rne(float f) {
  union { float f; unsigned int u; } c; c.f = f;
  unsigned int u = c.u;
  return (ushort_t)((u + 0x7FFFu + ((u >> 16) & 1u)) >> 16);
}
__device__ __forceinline__ void gload16(const void* g, void* l) {
  __builtin_amdgcn_global_load_lds(
      (const __attribute__((address_space(1))) void*)g,
      (__attribute__((address_space(3))) void*)l, 16, 0, 0);
}
// DPP quad-perm add (single-cycle VALU cross-lane within quads); CTRL literal
template<int CTRL>
__device__ __forceinline__ float dpp_add(float x) {
  int v = __builtin_amdgcn_update_dpp(0, __float_as_int(x), CTRL, 0xF, 0xF, true);
  return x + __int_as_float(v);
}

// ---------- launch 1: convert 4 MFMA tensors f32->bf16; blocks 0..19 zero cur ----------
__global__ void conv_k(const float* __restrict__ s_rel, const float* __restrict__ s_bin,
                       const float* __restrict__ s_wattn, const float* __restrict__ s_waggr,
                       ushort_t* __restrict__ dst, int* __restrict__ cur) {
  int b = blockIdx.x;
  if (b < 20) {
    int i = b * 256 + threadIdx.x;
    if (i < NREL) cur[i] = 0;
  }
  const int O1 = REL_N, O2 = O1 + BIN_N, O3 = O2 + WATTN_N;
  int i4 = (b * 256 + threadIdx.x) * 4;
  const float* src; int j;
  if (i4 < O1)      { src = s_rel;   j = i4; }
  else if (i4 < O2) { src = s_bin;   j = i4 - O1; }
  else if (i4 < O3) { src = s_wattn; j = i4 - O2; }
  else              { src = s_waggr; j = i4 - O3; }
  float4 v = *(const float4*)(src + j);
  short4v o;
  o[0] = (short)f2b_rne(v.x); o[1] = (short)f2b_rne(v.y);
  o[2] = (short)f2b_rne(v.z); o[3] = (short)f2b_rne(v.w);
  *(short4v*)(dst + i4) = o;
}

// ---------- launch 2: gload_lds GEMM (64x128, BK=64, XOR swizzle) + bucket-scatter
__global__ __launch_bounds__(256) void gemm_scatter_k(
    const ushort_t* __restrict__ c_rel, const ushort_t* __restrict__ c_bin,
    const ushort_t* __restrict__ c_wattn, const float* __restrict__ b_attn,
    const ushort_t* __restrict__ c_waggr, const float* __restrict__ b_aggr,
    ushort_t* __restrict__ P1B, ushort_t* __restrict__ PM, ushort_t* __restrict__ P2,
    const int* __restrict__ trip, int* __restrict__ cur, unsigned int* __restrict__ etb)
{
  __shared__ ushort_t Alds[64 * 64];    // 8 KB
  __shared__ ushort_t Blds[128 * 64];   // 16 KB
  int bx = blockIdx.x, by = blockIdx.y;
  if (by >= 12) {
    int sid = (by - 12) * 80 + bx;      // 0..319
    for (int i = threadIdx.x; i < 625; i += 256) {
      int e = sid * 625 + i;            // 320*625 = 200000 exact
      int h  = trip[3 * e];
      int ta = trip[3 * e + 1];
      int bi = trip[3 * e + 2];
      h  = min(max(h, 0), NREL - 1);
      ta = min(max(ta, 0), NREL - 1);
      bi = min(max(bi, 0), NBIN - 1);
      int p = atomicAdd(&cur[h], 1);
      if (p < CAP)
        etb[(h << 8) + p] = ((unsigned int)ta << 11) | ((unsigned int)bi << 24);
    }
    return;
  }
  const ushort_t* A; int Arows;
  const ushort_t* Bbase; int Bld; int joff;
  const float* bias;
  ushort_t* OUT; int OUTld; int ocolOff;
  int rbase;
  if (bx == 79) {
    if (by >= 4) return;
    A = c_bin; Arows = NBIN; rbase = 0;
    Bbase = c_wattn + 512; Bld = 3 * DIM; joff = 0;
    bias = b_attn;
    OUT = P2; OUTld = DIM; ocolOff = 0;
  } else {
    A = c_rel; Arows = NREL; rbase = bx * 64;
    int seg = by >> 2;
    if (seg == 2)      { Bbase = c_waggr;        Bld = DIM;     bias = b_aggr; }
    else if (seg == 1) { Bbase = c_wattn + 1024; Bld = 3 * DIM; bias = nullptr; }
    else               { Bbase = c_wattn;        Bld = 3 * DIM; bias = nullptr; }
    joff = seg * 512;
    OUT = (seg == 0) ? P1B : PM;
    OUTld = (seg == 0) ? DIM : 1024;
    ocolOff = (seg == 0) ? 0 : 512;
  }
  int tid = threadIdx.x;
  int l = tid & 63, wv = tid >> 6;
  int ctb = by * 128;
  int lr = l >> 3;
  int srcslot = (l & 7) ^ lr;           // pre-swizzled global k-slot (XOR involution)
  const ushort_t* aS0; const ushort_t* aS1;
  const ushort_t* bS0; const ushort_t* bS1; const ushort_t* bS2; const ushort_t* bS3;
  {
    int a0 = wv * 16 + 0 * 8 + lr, a1 = wv * 16 + 1 * 8 + lr;
    aS0 = A + (size_t)min(rbase + a0, Arows - 1) * DIM + srcslot * 8;
    aS1 = A + (size_t)min(rbase + a1, Arows - 1) * DIM + srcslot * 8;
    int c0 = wv * 32 + 0 * 8 + lr, c1 = wv * 32 + 1 * 8 + lr,
        c2 = wv * 32 + 2 * 8 + lr, c3 = wv * 32 + 3 * 8 + lr;
    bS0 = Bbase + (size_t)(ctb + c0 - joff) * Bld + srcslot * 8;
    bS1 = Bbase + (size_t)(ctb + c1 - joff) * Bld + srcslot * 8;
    bS2 = Bbase + (size_t)(ctb + c2 - joff) * Bld + srcslot * 8;
    bS3 = Bbase + (size_t)(ctb + c3 - joff) * Bld + srcslot * 8;
  }
  ushort_t* aD0 = Alds + (wv * 16 + 0) * 64;
  ushort_t* aD1 = Alds + (wv * 16 + 8) * 64;
  ushort_t* bD0 = Blds + (wv * 32 + 0) * 64;
  ushort_t* bD1 = Blds + (wv * 32 + 8) * 64;
  ushort_t* bD2 = Blds + (wv * 32 + 16) * 64;
  ushort_t* bD3 = Blds + (wv * 32 + 24) * 64;

  f32x4 acc[4][2] = {};
  for (int kk = 0; kk < DIM; kk += 64) {
    gload16(aS0 + kk, aD0); gload16(aS1 + kk, aD1);
    gload16(bS0 + kk, bD0); gload16(bS1 + kk, bD1);
    gload16(bS2 + kk, bD2); gload16(bS3 + kk, bD3);
    __syncthreads();                    // drains vmcnt before barrier
#pragma unroll
    for (int ks = 0; ks < 2; ++ks) {
      int sg = ks * 4 + (l >> 4);
      int sw = (sg ^ (l & 7)) * 8;      // swizzled LDS slot offset (elems)
      short8 aF[4], bF[2];
#pragma unroll
      for (int m2 = 0; m2 < 4; ++m2) {
        int mrow = m2 * 16 + (l & 15);
        aF[m2] = *(const short8*)(Alds + mrow * 64 + sw);
      }
#pragma unroll
      for (int n = 0; n < 2; ++n) {
        int crow = wv * 32 + n * 16 + (l & 15);
        bF[n] = *(const short8*)(Blds + crow * 64 + sw);
      }
#pragma unroll
      for (int m2 = 0; m2 < 4; ++m2)
#pragma unroll
        for (int n = 0; n < 2; ++n)
          acc[m2][n] = __builtin_amdgcn_mfma_f32_16x16x32_bf16(aF[m2], bF[n], acc[m2][n], 0, 0, 0);
    }
    __syncthreads();                    // all ds_reads done before restage
  }
  int r0 = rbase + (l >> 4) * 4;
#pragma unroll
  for (int n = 0; n < 2; ++n) {
    int col = ctb + wv * 32 + n * 16 + (l & 15);
    float bv = bias ? bias[col - joff] : 0.0f;
    int ocol = col - ocolOff;
#pragma unroll
    for (int m2 = 0; m2 < 4; ++m2) {
#pragma unroll
      for (int jj = 0; jj < 4; ++jj) {
        int row = r0 + m2 * 16 + jj;
        if (row < Arows) OUT[(size_t)row * OUTld + ocol] = f2b_rne(acc[m2][n][jj] + bv);
      }
    }
  }
}

// ---------- launch 3: aggregation — 3-deep edge pipeline at (256,4) cap=128 ----------
#define EDGE_LOAD(TB, P2V, P3V, MV)                                     \
  {                                                                     \
    const char* row_ = PMc + ((TB) & 0x00FFFFFFu);                      \
    P2V = *(const short8*)(p2lds + (((TB) >> 24) << 10) + l16);         \
    P3V = *(const short8*)(row_ + l16);                                 \
    MV  = *(const short8*)(row_ + 1024 + l16);                          \
  }

#define EDGE_COMPUTE(P2V, P3V, MV)                                      \
  {                                                                     \
    float part = 0.0f;                                                  \
    _Pragma("unroll")                                                   \
    for (int j = 0; j < 8; ++j) {                                       \
      float z = p1v[j] + b2f((ushort_t)P2V[j]) + b2f((ushort_t)P3V[j]); \
      part += z * (z > 0.f ? avv[j] : avv02[j]);                        \
    }                                                                   \
    part = dpp_add<0xB1>(part);   /* xor 1 (quad_perm [1,0,3,2]) */     \
    part = dpp_add<0x4E>(part);   /* xor 2 (quad_perm [2,3,0,1]) */     \
    part += __shfl_xor(part, 4);                                        \
    if (part > m + 8.0f) {                                              \
      float f = __expf(m - part);                                       \
      s *= f;                                                           \
      _Pragma("unroll")                                                 \
      for (int j = 0; j < 8; ++j) acc[j] *= f;                          \
      m = part;                                                         \
    }                                                                   \
    float ev = __expf(part - m);                                        \
    s += ev;                                                            \
    _Pragma("unroll")                                                   \
    for (int j = 0; j < 8; ++j) acc[j] += ev * b2f((ushort_t)MV[j]);    \
  }

#define GET_TB(I) ((unsigned int)__shfl((int)tbreg, (I)))

__global__ __launch_bounds__(256, 4) void aggr2_k(
    const int* __restrict__ cur, const unsigned int* __restrict__ etb,
    const ushort_t* __restrict__ P1B, const ushort_t* __restrict__ PM,
    const ushort_t* __restrict__ P2, const float* __restrict__ avec,
    float* __restrict__ outf)
{
  // shmem phase 1: [0,32768) = P2 copy (bf16 32x512)
  // shmem phase 2: [0,8192) = red[4][512] f32; [8192,8448) = ms[4][8][2] f32
  __shared__ __align__(16) char shmem[32 * DIM * 2];

  int t = threadIdx.x;
  int l = t & 63, wv = t >> 6;
  int p = wv >> 1, sub = wv & 1;
  int r = blockIdx.x * 2 + p;
  int nE = min(cur[r], CAP);
  int base = r << 8;                // bucket base in etb
  int half = nE >> 1;
  int start = sub ? half : 0;
  int cnt = sub ? (nE - half) : half;

  int hd1 = l >> 3;
  int ob = l * 8;
  int l16 = l * 16;

  // ---- preload all of P2 (32 KB) into LDS: 8 x short8 per thread ----
  {
    ushort_t* p2dst = (ushort_t*)shmem;
#pragma unroll
    for (int i = 0; i < 8; ++i) {
      int idx = t * 8 + i * 2048;
      *(short8*)(p2dst + idx) = *(const short8*)(P2 + idx);
    }
  }

  float p1v[8], avv[8], avv02[8];
  {
    short8 p1b = *(const short8*)(P1B + (size_t)r * DIM + ob);
#pragma unroll
    for (int j = 0; j < 8; ++j) {
      p1v[j] = b2f((ushort_t)p1b[j]);
      float a = avec[ob + j];
      avv[j] = a;
      avv02[j] = 0.2f * a;
    }
  }
  float acc[8] = {};
  float m = -INFINITY, s = 0.0f;

  const char* PMc = (const char*)PM;
  const char* p2lds = (const char*)shmem;

  __syncthreads();                  // P2 staged before any edge reads it

  for (int ck = 0; ck < cnt; ck += 64) {
    int ne = min(64, cnt - ck);
    unsigned int tbreg = 0;
    if (l < ne) tbreg = etb[base + start + ck + l];
    short8 p2A, p3A, mvA, p2B, p3B, mvB, p2C, p3C, mvC;
    if (ne > 0) { unsigned int tb = GET_TB(0); EDGE_LOAD(tb, p2A, p3A, mvA); }
    if (ne > 1) { unsigned int tb = GET_TB(1); EDGE_LOAD(tb, p2B, p3B, mvB); }
    if (ne > 2) { unsigned int tb = GET_TB(2); EDGE_LOAD(tb, p2C, p3C, mvC); }
    int i = 0;
    while (i + 3 <= ne) {
      EDGE_COMPUTE(p2A, p3A, mvA);
      if (i + 3 < ne) { unsigned int tb = GET_TB(i + 3); EDGE_LOAD(tb, p2A, p3A, mvA); }
      EDGE_COMPUTE(p2B, p3B, mvB);
      if (i + 4 < ne) { unsigned int tb = GET_TB(i + 4); EDGE_LOAD(tb, p2B, p3B, mvB); }
      EDGE_COMPUTE(p2C, p3C, mvC);
      if (i + 5 < ne) { unsigned int tb = GET_TB(i + 5); EDGE_LOAD(tb, p2C, p3C, mvC); }
      i += 3;
    }
    int rem = ne - i;
    if (rem > 0) EDGE_COMPUTE(p2A, p3A, mvA);
    if (rem > 1) EDGE_COMPUTE(p2B, p3B, mvB);
    if (rem > 2) EDGE_COMPUTE(p2C, p3C, mvC);
  }

  // ---- merge the two half-relation waves (reuse shmem: red + ms overlay) ----
  __syncthreads();                  // all waves done reading P2 from shmem
  float* red = (float*)shmem;                       // [4][512]
  float* ms  = (float*)(shmem + 8192);              // [4][8][2]
#pragma unroll
  for (int j = 0; j < 8; ++j) red[wv * DIM + ob + j] = acc[j];
  if ((l & 7) == 0) { ms[(wv * NHEAD + hd1) * 2] = m; ms[(wv * NHEAD + hd1) * 2 + 1] = s; }
  __syncthreads();

  int pp = t >> 7;
  int d0 = (t & 127) * 4;
  int h = d0 >> 6;
  int rr = blockIdx.x * 2 + pp;
  float m1 = ms[((2 * pp) * NHEAD + h) * 2],     s1 = ms[((2 * pp) * NHEAD + h) * 2 + 1];
  float m2 = ms[((2 * pp + 1) * NHEAD + h) * 2], s2 = ms[((2 * pp + 1) * NHEAD + h) * 2 + 1];
  float M = fmaxf(m1, m2);
  float c1 = (m1 == M) ? 1.0f : __expf(m1 - M);
  float c2 = (m2 == M) ? 1.0f : __expf(m2 - M);
  float S = s1 * c1 + s2 * c2;
  float inv = 1.0f / (S + 1e-16f);
  float4 val;
  val.x = (red[(2 * pp) * DIM + d0]     * c1 + red[(2 * pp + 1) * DIM + d0]     * c2) * inv;
  val.y = (red[(2 * pp) * DIM + d0 + 1] * c1 + red[(2 * pp + 1) * DIM + d0 + 1] * c2) * inv;
  val.z = (red[(2 * pp) * DIM + d0 + 2] * c1 + red[(2 * pp + 1) * DIM + d0 + 2] * c2) * inv;
  val.w = (red[(2 * pp) * DIM + d0 + 3] * c1 + red[(2 * pp + 1) * DIM + d0 + 3] * c2) * inv;
  *(float4*)(outf + (size_t)rr * DIM + d0) = val;
}

extern "C" void kernel_launch(void* const* d_in, const int* in_sizes, int n_in,
                              void* d_out, int out_size, void* d_ws, size_t ws_size,
                              hipStream_t stream) {
  const float* s_rel   = (const float*)d_in[0];
  const float* s_bin   = (const float*)d_in[1];
  const int*   trip    = (const int*)d_in[2];     // int32
  const float* s_wattn = (const float*)d_in[3];
  const float* b_attn  = (const float*)d_in[4];
  const float* avec    = (const float*)d_in[5];
  const float* s_waggr = (const float*)d_in[6];
  const float* b_aggr  = (const float*)d_in[7];

  ushort_t* canon = (ushort_t*)d_ws;
  ushort_t* c_rel   = canon;
  ushort_t* c_bin   = c_rel + REL_N;
  ushort_t* c_wattn = c_bin + BIN_N;
  ushort_t* c_waggr = c_wattn + WATTN_N;
  int* cur = (int*)(c_waggr + WAGGR_N);             // NREL
  unsigned int* etb = (unsigned int*)(cur + NREL);  // NREL*CAP
  ushort_t* P1B = (ushort_t*)(((uintptr_t)(etb + NREL * CAP) + 15) & ~(uintptr_t)15);
  ushort_t* PM  = P1B + (size_t)NREL * DIM;
  ushort_t* P2  = PM + (size_t)NREL * 1024;

  conv_k<<<CONV_BLOCKS, 256, 0, stream>>>(s_rel, s_bin, s_wattn, s_waggr, canon, cur);

  dim3 gg(80, 16);
  gemm_scatter_k<<<gg, 256, 0, stream>>>(c_rel, c_bin, c_wattn, b_attn, c_waggr, b_aggr,
                                         P1B, PM, P2, trip, cur, etb);

  aggr2_k<<<NREL / 2, 256, 0, stream>>>(cur, etb, P1B, PM, P2, avec, (float*)d_out);
}